// Round 2
// baseline (62.109 us; speedup 1.0000x reference)
//
#include <hip/hip_runtime.h>
#include <hip/hip_bf16.h>
#include <math.h>

typedef short short8 __attribute__((ext_vector_type(8)));
typedef float f32x4 __attribute__((ext_vector_type(4)));

#define NQ 32
#define NDOCS 8
#define QLEN 32
#define DLEN 200
#define DIM 128
#define MD 256          // total docs
#define ROWB 256        // LDS row stride bytes (128 bf16)

__device__ __forceinline__ short f2bf(float x) {
    union { float f; unsigned u; } v; v.f = x;
    unsigned r = v.u + 0x7FFFu + ((v.u >> 16) & 1u);  // RNE
    return (short)(r >> 16);
}

__device__ __forceinline__ short8 cvt8(float4 f0, float4 f1) {
    short8 o;
    o[0] = f2bf(f0.x); o[1] = f2bf(f0.y); o[2] = f2bf(f0.z); o[3] = f2bf(f0.w);
    o[4] = f2bf(f1.x); o[5] = f2bf(f1.y); o[6] = f2bf(f1.z); o[7] = f2bf(f1.w);
    return o;
}

// hq fp32 -> bf16 (131072 elems)
__global__ __launch_bounds__(256) void convert_hq(const float* __restrict__ hq,
                                                  short* __restrict__ hqb) {
    int idx = blockIdx.x * 256 + threadIdx.x;
    const float4* p = reinterpret_cast<const float4*>(hq) + (size_t)idx * 2;
    reinterpret_cast<short8*>(hqb)[idx] = cvt8(p[0], p[1]);
}

// chunk c (8 bf16): row=c>>4, kc=c&15; XOR-swizzled LDS write
__device__ __forceinline__ void writeChunk(char* lds, int c, float4 f0, float4 f1) {
    int row = c >> 4, kc = c & 15;
    int byte = row * ROWB + ((kc * 16) ^ ((row & 7) << 4));
    *reinterpret_cast<short8*>(&lds[byte]) = cvt8(f0, f1);
}

// One block (1024 thr, 16 waves) per doc m. Wave w computes questions {2w, 2w+1}.
// C = mfma(hd_frag, hq_frag): lane holds C[d = dt*16 + lg*4 + r][q = qt*16 + lr].
__global__ __launch_bounds__(1024, 4) void colbert_scores(const float* __restrict__ hd,
                                                          const short* __restrict__ hqb,
                                                          float* __restrict__ out) {
    __shared__ char lds[208 * ROWB];  // 53248 B; rows 200..207 garbage (masked)
    const int m = blockIdx.x;
    const int tid = threadIdx.x;
    const float* src = hd + (size_t)m * (DLEN * DIM);
    const float4* src4 = reinterpret_cast<const float4*>(src);

    // ---- issue half1 loads: rows 0..95 = chunks [0,1536) ----
    float4 p0a = src4[tid * 2], p0b = src4[tid * 2 + 1];
    float4 p1a, p1b;
    const bool has1 = tid < 512;
    if (has1) { p1a = src4[(tid + 1024) * 2]; p1b = src4[(tid + 1024) * 2 + 1]; }

    // ---- A-fragments (hq, bf16) for this wave's 2 questions ----
    const int wid = tid >> 6, lane = tid & 63;
    const int lg = lane >> 4, lr = lane & 15;
    const int n0 = wid * 2;
    short8 a[2][2][4];
    #pragma unroll
    for (int nn = 0; nn < 2; ++nn)
        #pragma unroll
        for (int qt = 0; qt < 2; ++qt)
            #pragma unroll
            for (int s = 0; s < 4; ++s)
                a[nn][qt][s] = *reinterpret_cast<const short8*>(
                    hqb + ((size_t)((n0 + nn) * QLEN + qt * 16 + lr) * DIM + s * 32 + lg * 8));

    // ---- issue half2 loads: rows 96..199 = chunks [1536,3200) ----
    float4 q0a = src4[(1536 + tid) * 2], q0b = src4[(1536 + tid) * 2 + 1];
    float4 q1a, q1b;
    const bool has3 = tid < 640;
    if (has3) { q1a = src4[(2560 + tid) * 2]; q1b = src4[(2560 + tid) * 2 + 1]; }

    // ---- convert + write half1, barrier ----
    writeChunk(lds, tid, p0a, p0b);
    if (has1) writeChunk(lds, tid + 1024, p1a, p1b);
    __syncthreads();

    // per-lane ds_read addresses for the 4 k-slices (swizzle folded in)
    int va[4];
    const int pre = ((lg ^ (lr & 7)) << 4);
    #pragma unroll
    for (int s = 0; s < 4; ++s) va[s] = lr * ROWB + (pre ^ (s << 6));

    float qmax00 = -INFINITY, qmax01 = -INFINITY, qmax10 = -INFINITY, qmax11 = -INFINITY;

#define STEP(DT, MASKED)                                                          \
    {                                                                             \
        f32x4 acc00 = {0,0,0,0}, acc01 = {0,0,0,0}, acc10 = {0,0,0,0}, acc11 = {0,0,0,0}; \
        _Pragma("unroll")                                                         \
        for (int s = 0; s < 4; ++s) {                                             \
            short8 b = *reinterpret_cast<const short8*>(&lds[va[s] + (DT) * 4096]); \
            acc00 = __builtin_amdgcn_mfma_f32_16x16x32_bf16(b, a[0][0][s], acc00, 0, 0, 0); \
            acc01 = __builtin_amdgcn_mfma_f32_16x16x32_bf16(b, a[0][1][s], acc01, 0, 0, 0); \
            acc10 = __builtin_amdgcn_mfma_f32_16x16x32_bf16(b, a[1][0][s], acc10, 0, 0, 0); \
            acc11 = __builtin_amdgcn_mfma_f32_16x16x32_bf16(b, a[1][1][s], acc11, 0, 0, 0); \
        }                                                                         \
        if (!(MASKED) || lg < 2) {                                                \
            qmax00 = fmaxf(qmax00, fmaxf(fmaxf(acc00[0], acc00[1]), fmaxf(acc00[2], acc00[3]))); \
            qmax01 = fmaxf(qmax01, fmaxf(fmaxf(acc01[0], acc01[1]), fmaxf(acc01[2], acc01[3]))); \
            qmax10 = fmaxf(qmax10, fmaxf(fmaxf(acc10[0], acc10[1]), fmaxf(acc10[2], acc10[3]))); \
            qmax11 = fmaxf(qmax11, fmaxf(fmaxf(acc11[0], acc11[1]), fmaxf(acc11[2], acc11[3]))); \
        }                                                                         \
    }

    // rows 0..95
    #pragma unroll
    for (int dt = 0; dt < 6; ++dt) STEP(dt, false);

    // convert + write half2 (loads completed under the compute above)
    writeChunk(lds, 1536 + tid, q0a, q0b);
    if (has3) writeChunk(lds, 2560 + tid, q1a, q1b);
    __syncthreads();

    // rows 96..199 (+pad)
    #pragma unroll
    for (int dt = 6; dt < 12; ++dt) STEP(dt, false);
    STEP(12, true);
#undef STEP

    // max over d: reduce across lg groups (lanes ^16, ^32)
    #pragma unroll
    for (int off = 16; off <= 32; off <<= 1) {
        qmax00 = fmaxf(qmax00, __shfl_xor(qmax00, off, 64));
        qmax01 = fmaxf(qmax01, __shfl_xor(qmax01, off, 64));
        qmax10 = fmaxf(qmax10, __shfl_xor(qmax10, off, 64));
        qmax11 = fmaxf(qmax11, __shfl_xor(qmax11, off, 64));
    }
    // mean over q: qt0+qt1, then sum across lr lanes (all lg groups identical now)
    float s0 = qmax00 + qmax01;
    float s1 = qmax10 + qmax11;
    #pragma unroll
    for (int off = 1; off <= 8; off <<= 1) {
        s0 += __shfl_xor(s0, off, 64);
        s1 += __shfl_xor(s1, off, 64);
    }
    if (lane == 0) {
        out[(size_t)n0 * MD + m] = s0 * (1.0f / 32.0f);
        out[(size_t)(n0 + 1) * MD + m] = s1 * (1.0f / 32.0f);
    }
}

// loss = mean_n( logsumexp(row_n) - row_n[8n] )
__global__ __launch_bounds__(256) void colbert_loss(const float* __restrict__ scores,
                                                    float* __restrict__ loss_out) {
    __shared__ float terms[NQ];
    const int tid = threadIdx.x;
    const int wid = tid >> 6, lane = tid & 63;
    for (int n = wid; n < NQ; n += 4) {
        const float* row = scores + n * MD;
        float v0 = row[lane], v1 = row[64 + lane], v2 = row[128 + lane], v3 = row[192 + lane];
        float mx = fmaxf(fmaxf(v0, v1), fmaxf(v2, v3));
        #pragma unroll
        for (int off = 1; off < 64; off <<= 1) mx = fmaxf(mx, __shfl_xor(mx, off, 64));
        float s = expf(v0 - mx) + expf(v1 - mx) + expf(v2 - mx) + expf(v3 - mx);
        #pragma unroll
        for (int off = 1; off < 64; off <<= 1) s += __shfl_xor(s, off, 64);
        if (lane == 0) terms[n] = (mx + logf(s)) - row[n * NDOCS];
    }
    __syncthreads();
    if (tid == 0) {
        float acc = 0.f;
        #pragma unroll
        for (int n = 0; n < NQ; ++n) acc += terms[n];
        loss_out[0] = acc * (1.0f / NQ);
    }
}

extern "C" void kernel_launch(void* const* d_in, const int* in_sizes, int n_in,
                              void* d_out, int out_size, void* d_ws, size_t ws_size,
                              hipStream_t stream) {
    const float* hq = (const float*)d_in[0];   // [32][32][128] f32
    const float* hd = (const float*)d_in[1];   // [256][200][128] f32
    float* out = (float*)d_out;                // 8192 scores + 1 loss
    short* hqb = (short*)d_ws;                 // 131072 bf16

    convert_hq<<<64, 256, 0, stream>>>(hq, hqb);
    colbert_scores<<<MD, 1024, 0, stream>>>(hd, hqb, out);
    colbert_loss<<<1, 256, 0, stream>>>(out, out + NQ * MD);
}

// Round 3
// 45.243 us; speedup vs baseline: 1.3728x; 1.3728x over previous
//
#include <hip/hip_runtime.h>
#include <hip/hip_bf16.h>
#include <math.h>

typedef short short8 __attribute__((ext_vector_type(8)));
typedef float f32x4 __attribute__((ext_vector_type(4)));

#define NQ 32
#define NDOCS 8
#define QLEN 32
#define DLEN 200
#define DIM 128
#define MD 256          // total docs
#define ROWB 256        // LDS row stride bytes (128 bf16)

__device__ __forceinline__ short f2bf(float x) {
    union { float f; unsigned u; } v; v.f = x;
    unsigned r = v.u + 0x7FFFu + ((v.u >> 16) & 1u);  // RNE
    return (short)(r >> 16);
}

__device__ __forceinline__ short8 cvt8(float4 f0, float4 f1) {
    short8 o;
    o[0] = f2bf(f0.x); o[1] = f2bf(f0.y); o[2] = f2bf(f0.z); o[3] = f2bf(f0.w);
    o[4] = f2bf(f1.x); o[5] = f2bf(f1.y); o[6] = f2bf(f1.z); o[7] = f2bf(f1.w);
    return o;
}

// chunk c (8 bf16): row=c>>4, kc=c&15; XOR-swizzled LDS write
__device__ __forceinline__ void writeChunk(char* lds, int c, float4 f0, float4 f1) {
    int row = c >> 4, kc = c & 15;
    int byte = row * ROWB + ((kc * 16) ^ ((row & 7) << 4));
    *reinterpret_cast<short8*>(&lds[byte]) = cvt8(f0, f1);
}

// One block (1024 thr, 16 waves, 4 waves/SIMD) per doc m.
// Wave w computes questions {2w, 2w+1}.
// C = mfma(hd_frag, hq_frag): lane holds C[d = dt*16 + lg*4 + r][q = qt*16 + lr].
__global__ __launch_bounds__(1024, 4) void colbert_scores(const float* __restrict__ hd,
                                                          const float* __restrict__ hq,
                                                          float* __restrict__ out) {
    __shared__ char lds[208 * ROWB];  // 53248 B; rows 200..207 zeroed (and masked)
    const int m = blockIdx.x;
    const int tid = threadIdx.x;
    const float4* src4 = reinterpret_cast<const float4*>(hd + (size_t)m * (DLEN * DIM));

    // ---- stage hd[m]: fp32 -> bf16 LDS, swizzled; nothing held across compute ----
    for (int c = tid; c < 3200; c += 1024) {
        float4 f0 = src4[c * 2], f1 = src4[c * 2 + 1];
        writeChunk(lds, c, f0, f1);
    }
    if (tid < 128) {  // zero pad rows 200..207
        float4 z = {0.f, 0.f, 0.f, 0.f};
        writeChunk(lds, 3200 + tid, z, z);
    }

    // ---- A-fragments: convert this wave's 2 questions from fp32 hq (L2-resident) ----
    const int wid = tid >> 6, lane = tid & 63;
    const int lg = lane >> 4, lr = lane & 15;
    const int n0 = wid * 2;
    const float4* hq4 = reinterpret_cast<const float4*>(hq);
    short8 a[2][2][4];
    #pragma unroll
    for (int nn = 0; nn < 2; ++nn)
        #pragma unroll
        for (int qt = 0; qt < 2; ++qt)
            #pragma unroll
            for (int s = 0; s < 4; ++s) {
                int e4 = ((n0 + nn) * QLEN + qt * 16 + lr) * (DIM / 4) + s * 8 + lg * 2;
                a[nn][qt][s] = cvt8(hq4[e4], hq4[e4 + 1]);
            }

    __syncthreads();

    // per-lane ds_read addresses for the 4 k-slices (swizzle folded in)
    int va[4];
    const int pre = ((lg ^ (lr & 7)) << 4);
    #pragma unroll
    for (int s = 0; s < 4; ++s) va[s] = lr * ROWB + (pre ^ (s << 6));

    float qmax00 = -INFINITY, qmax01 = -INFINITY, qmax10 = -INFINITY, qmax11 = -INFINITY;

#define STEP(DT, MASKED)                                                          \
    {                                                                             \
        f32x4 acc00 = {0,0,0,0}, acc01 = {0,0,0,0}, acc10 = {0,0,0,0}, acc11 = {0,0,0,0}; \
        _Pragma("unroll")                                                         \
        for (int s = 0; s < 4; ++s) {                                             \
            short8 b = *reinterpret_cast<const short8*>(&lds[va[s] + (DT) * 4096]); \
            acc00 = __builtin_amdgcn_mfma_f32_16x16x32_bf16(b, a[0][0][s], acc00, 0, 0, 0); \
            acc01 = __builtin_amdgcn_mfma_f32_16x16x32_bf16(b, a[0][1][s], acc01, 0, 0, 0); \
            acc10 = __builtin_amdgcn_mfma_f32_16x16x32_bf16(b, a[1][0][s], acc10, 0, 0, 0); \
            acc11 = __builtin_amdgcn_mfma_f32_16x16x32_bf16(b, a[1][1][s], acc11, 0, 0, 0); \
        }                                                                         \
        if (!(MASKED) || lg < 2) {                                                \
            qmax00 = fmaxf(qmax00, fmaxf(fmaxf(acc00[0], acc00[1]), fmaxf(acc00[2], acc00[3]))); \
            qmax01 = fmaxf(qmax01, fmaxf(fmaxf(acc01[0], acc01[1]), fmaxf(acc01[2], acc01[3]))); \
            qmax10 = fmaxf(qmax10, fmaxf(fmaxf(acc10[0], acc10[1]), fmaxf(acc10[2], acc10[3]))); \
            qmax11 = fmaxf(qmax11, fmaxf(fmaxf(acc11[0], acc11[1]), fmaxf(acc11[2], acc11[3]))); \
        }                                                                         \
    }

    #pragma unroll
    for (int dt = 0; dt < 12; ++dt) STEP(dt, false);
    STEP(12, true);
#undef STEP

    // max over d: reduce across lg groups (lanes ^16, ^32)
    #pragma unroll
    for (int off = 16; off <= 32; off <<= 1) {
        qmax00 = fmaxf(qmax00, __shfl_xor(qmax00, off, 64));
        qmax01 = fmaxf(qmax01, __shfl_xor(qmax01, off, 64));
        qmax10 = fmaxf(qmax10, __shfl_xor(qmax10, off, 64));
        qmax11 = fmaxf(qmax11, __shfl_xor(qmax11, off, 64));
    }
    // mean over q: qt0+qt1, then sum across lr lanes
    float s0 = qmax00 + qmax01;
    float s1 = qmax10 + qmax11;
    #pragma unroll
    for (int off = 1; off <= 8; off <<= 1) {
        s0 += __shfl_xor(s0, off, 64);
        s1 += __shfl_xor(s1, off, 64);
    }
    if (lane == 0) {
        out[(size_t)n0 * MD + m] = s0 * (1.0f / 32.0f);
        out[(size_t)(n0 + 1) * MD + m] = s1 * (1.0f / 32.0f);
    }
}

// loss = mean_n( logsumexp(row_n) - row_n[8n] )
__global__ __launch_bounds__(256) void colbert_loss(const float* __restrict__ scores,
                                                    float* __restrict__ loss_out) {
    __shared__ float terms[NQ];
    const int tid = threadIdx.x;
    const int wid = tid >> 6, lane = tid & 63;
    for (int n = wid; n < NQ; n += 4) {
        const float* row = scores + n * MD;
        float v0 = row[lane], v1 = row[64 + lane], v2 = row[128 + lane], v3 = row[192 + lane];
        float mx = fmaxf(fmaxf(v0, v1), fmaxf(v2, v3));
        #pragma unroll
        for (int off = 1; off < 64; off <<= 1) mx = fmaxf(mx, __shfl_xor(mx, off, 64));
        float s = expf(v0 - mx) + expf(v1 - mx) + expf(v2 - mx) + expf(v3 - mx);
        #pragma unroll
        for (int off = 1; off < 64; off <<= 1) s += __shfl_xor(s, off, 64);
        if (lane == 0) terms[n] = (mx + logf(s)) - row[n * NDOCS];
    }
    __syncthreads();
    if (tid == 0) {
        float acc = 0.f;
        #pragma unroll
        for (int n = 0; n < NQ; ++n) acc += terms[n];
        loss_out[0] = acc * (1.0f / NQ);
    }
}

extern "C" void kernel_launch(void* const* d_in, const int* in_sizes, int n_in,
                              void* d_out, int out_size, void* d_ws, size_t ws_size,
                              hipStream_t stream) {
    const float* hq = (const float*)d_in[0];   // [32][32][128] f32
    const float* hd = (const float*)d_in[1];   // [256][200][128] f32
    float* out = (float*)d_out;                // 8192 scores + 1 loss

    colbert_scores<<<MD, 1024, 0, stream>>>(hd, hq, out);
    colbert_loss<<<1, 256, 0, stream>>>(out, out + NQ * MD);
}

// Round 4
// 44.802 us; speedup vs baseline: 1.3863x; 1.0098x over previous
//
#include <hip/hip_runtime.h>
#include <hip/hip_bf16.h>
#include <math.h>

typedef short short8 __attribute__((ext_vector_type(8)));
typedef float f32x4 __attribute__((ext_vector_type(4)));

#define NQ 32
#define NDOCS 8
#define QLEN 32
#define DLEN 200
#define DIM 128
#define MD 256          // total docs
#define ROWB 256        // LDS row stride bytes (128 bf16)

__device__ __forceinline__ short f2bf(float x) {
    union { float f; unsigned u; } v; v.f = x;
    unsigned r = v.u + 0x7FFFu + ((v.u >> 16) & 1u);  // RNE
    return (short)(r >> 16);
}

__device__ __forceinline__ short8 cvt8(float4 f0, float4 f1) {
    short8 o;
    o[0] = f2bf(f0.x); o[1] = f2bf(f0.y); o[2] = f2bf(f0.z); o[3] = f2bf(f0.w);
    o[4] = f2bf(f1.x); o[5] = f2bf(f1.y); o[6] = f2bf(f1.z); o[7] = f2bf(f1.w);
    return o;
}

// chunk c (8 bf16): row=c>>4, kc=c&15; XOR-swizzled LDS write
__device__ __forceinline__ void writeChunk(char* lds, int c, float4 f0, float4 f1) {
    int row = c >> 4, kc = c & 15;
    int byte = row * ROWB + ((kc * 16) ^ ((row & 7) << 4));
    *reinterpret_cast<short8*>(&lds[byte]) = cvt8(f0, f1);
}

// One block (1024 thr, 16 waves, exactly 4 waves/SIMD) per doc m.
// Wave w computes questions {2w, 2w+1}.
// C = mfma(hd_frag, hq_frag): lane holds C[d = dt*16 + lg*4 + r][q = qt*16 + lr].
__global__ __launch_bounds__(1024, 4)
__attribute__((amdgpu_waves_per_eu(4, 4)))  // pin 4 waves/EU -> 128-VGPR cap, no spill
void colbert_scores(const float* __restrict__ hd,
                    const float* __restrict__ hq,
                    float* __restrict__ out) {
    __shared__ char lds[208 * ROWB];  // 53248 B; rows 200..207 zeroed (and masked)
    const int m = blockIdx.x;
    const int tid = threadIdx.x;
    const float4* src4 = reinterpret_cast<const float4*>(hd + (size_t)m * (DLEN * DIM));

    // ---- stage hd[m]: issue ALL loads first (one HBM latency), then cvt+ds_write ----
    const bool t4 = tid < 128;
    float4 f0a = src4[tid * 2],          f0b = src4[tid * 2 + 1];
    float4 f1a = src4[(tid + 1024) * 2], f1b = src4[(tid + 1024) * 2 + 1];
    float4 f2a = src4[(tid + 2048) * 2], f2b = src4[(tid + 2048) * 2 + 1];
    float4 f3a = {0, 0, 0, 0}, f3b = {0, 0, 0, 0};
    if (t4) { f3a = src4[(tid + 3072) * 2]; f3b = src4[(tid + 3072) * 2 + 1]; }

    writeChunk(lds, tid, f0a, f0b);
    writeChunk(lds, tid + 1024, f1a, f1b);
    writeChunk(lds, tid + 2048, f2a, f2b);
    if (t4) {
        writeChunk(lds, tid + 3072, f3a, f3b);
        float4 z = {0, 0, 0, 0};
        writeChunk(lds, tid + 3200, z, z);  // zero pad rows 200..207
    }

    // ---- A-fragments: convert this wave's 2 questions from fp32 hq (L2-resident) ----
    const int wid = tid >> 6, lane = tid & 63;
    const int lg = lane >> 4, lr = lane & 15;
    const int n0 = wid * 2;
    const float4* hq4 = reinterpret_cast<const float4*>(hq);
    short8 a[2][2][4];
    #pragma unroll
    for (int nn = 0; nn < 2; ++nn)
        #pragma unroll
        for (int qt = 0; qt < 2; ++qt)
            #pragma unroll
            for (int s = 0; s < 4; ++s) {
                int e4 = ((n0 + nn) * QLEN + qt * 16 + lr) * (DIM / 4) + s * 8 + lg * 2;
                a[nn][qt][s] = cvt8(hq4[e4], hq4[e4 + 1]);
            }

    __syncthreads();

    // per-lane ds_read addresses for the 4 k-slices (swizzle folded in)
    int va[4];
    const int pre = ((lg ^ (lr & 7)) << 4);
    #pragma unroll
    for (int s = 0; s < 4; ++s) va[s] = lr * ROWB + (pre ^ (s << 6));

    float qmax00 = -INFINITY, qmax01 = -INFINITY, qmax10 = -INFINITY, qmax11 = -INFINITY;

#define STEP(DT, MASKED)                                                          \
    {                                                                             \
        f32x4 acc00 = {0,0,0,0}, acc01 = {0,0,0,0}, acc10 = {0,0,0,0}, acc11 = {0,0,0,0}; \
        _Pragma("unroll")                                                         \
        for (int s = 0; s < 4; ++s) {                                             \
            short8 b = *reinterpret_cast<const short8*>(&lds[va[s] + (DT) * 4096]); \
            acc00 = __builtin_amdgcn_mfma_f32_16x16x32_bf16(b, a[0][0][s], acc00, 0, 0, 0); \
            acc01 = __builtin_amdgcn_mfma_f32_16x16x32_bf16(b, a[0][1][s], acc01, 0, 0, 0); \
            acc10 = __builtin_amdgcn_mfma_f32_16x16x32_bf16(b, a[1][0][s], acc10, 0, 0, 0); \
            acc11 = __builtin_amdgcn_mfma_f32_16x16x32_bf16(b, a[1][1][s], acc11, 0, 0, 0); \
        }                                                                         \
        if (!(MASKED) || lg < 2) {                                                \
            qmax00 = fmaxf(qmax00, fmaxf(fmaxf(acc00[0], acc00[1]), fmaxf(acc00[2], acc00[3]))); \
            qmax01 = fmaxf(qmax01, fmaxf(fmaxf(acc01[0], acc01[1]), fmaxf(acc01[2], acc01[3]))); \
            qmax10 = fmaxf(qmax10, fmaxf(fmaxf(acc10[0], acc10[1]), fmaxf(acc10[2], acc10[3]))); \
            qmax11 = fmaxf(qmax11, fmaxf(fmaxf(acc11[0], acc11[1]), fmaxf(acc11[2], acc11[3]))); \
        }                                                                         \
    }

    #pragma unroll
    for (int dt = 0; dt < 12; ++dt) STEP(dt, false);
    STEP(12, true);
#undef STEP

    // max over d: reduce across lg groups (lanes ^16, ^32)
    #pragma unroll
    for (int off = 16; off <= 32; off <<= 1) {
        qmax00 = fmaxf(qmax00, __shfl_xor(qmax00, off, 64));
        qmax01 = fmaxf(qmax01, __shfl_xor(qmax01, off, 64));
        qmax10 = fmaxf(qmax10, __shfl_xor(qmax10, off, 64));
        qmax11 = fmaxf(qmax11, __shfl_xor(qmax11, off, 64));
    }
    // mean over q: qt0+qt1, then sum across lr lanes
    float s0 = qmax00 + qmax01;
    float s1 = qmax10 + qmax11;
    #pragma unroll
    for (int off = 1; off <= 8; off <<= 1) {
        s0 += __shfl_xor(s0, off, 64);
        s1 += __shfl_xor(s1, off, 64);
    }
    if (lane == 0) {
        out[(size_t)n0 * MD + m] = s0 * (1.0f / 32.0f);
        out[(size_t)(n0 + 1) * MD + m] = s1 * (1.0f / 32.0f);
    }
}

// loss = mean_n( logsumexp(row_n) - row_n[8n] )
__global__ __launch_bounds__(256) void colbert_loss(const float* __restrict__ scores,
                                                    float* __restrict__ loss_out) {
    __shared__ float terms[NQ];
    const int tid = threadIdx.x;
    const int wid = tid >> 6, lane = tid & 63;
    for (int n = wid; n < NQ; n += 4) {
        const float* row = scores + n * MD;
        float v0 = row[lane], v1 = row[64 + lane], v2 = row[128 + lane], v3 = row[192 + lane];
        float mx = fmaxf(fmaxf(v0, v1), fmaxf(v2, v3));
        #pragma unroll
        for (int off = 1; off < 64; off <<= 1) mx = fmaxf(mx, __shfl_xor(mx, off, 64));
        float s = expf(v0 - mx) + expf(v1 - mx) + expf(v2 - mx) + expf(v3 - mx);
        #pragma unroll
        for (int off = 1; off < 64; off <<= 1) s += __shfl_xor(s, off, 64);
        if (lane == 0) terms[n] = (mx + logf(s)) - row[n * NDOCS];
    }
    __syncthreads();
    if (tid == 0) {
        float acc = 0.f;
        #pragma unroll
        for (int n = 0; n < NQ; ++n) acc += terms[n];
        loss_out[0] = acc * (1.0f / NQ);
    }
}

extern "C" void kernel_launch(void* const* d_in, const int* in_sizes, int n_in,
                              void* d_out, int out_size, void* d_ws, size_t ws_size,
                              hipStream_t stream) {
    const float* hq = (const float*)d_in[0];   // [32][32][128] f32
    const float* hd = (const float*)d_in[1];   // [256][200][128] f32
    float* out = (float*)d_out;                // 8192 scores + 1 loss

    colbert_scores<<<MD, 1024, 0, stream>>>(hd, hq, out);
    colbert_loss<<<1, 256, 0, stream>>>(out, out + NQ * MD);
}